// Round 2
// baseline (230.246 us; speedup 1.0000x reference)
//
#include <hip/hip_runtime.h>

#define NROW 6
#define NCOL 6
#define BATCH 1024
#define NSITE 36

// LDS bank-conflict swizzle (R2): XOR dword-addr bits [4:2] with bits [7:5]
// and bits [4:3] with bits [9:8]. Preserves bits [1:0] (quads stay contiguous
// and 16B-aligned); source bits [9:5] unmodified => bijective; SWZ(0)==0.
// The [9:8] term spreads the fused-pair unit-id bits across bank bits so the
// 64-lane scalar read/write patterns land 2-way max (free) instead of 4-way.
__device__ __forceinline__ int SWZ(int a) {
    return a ^ (((a >> 5) & 7) << 2) ^ (((a >> 8) & 3) << 3);
}

// Wave-uniform scalar-memory pointer: address_space(4) = AMDGPU constant.
// Scalar float loads at uniform offsets merge into s_load_dwordx16 (SMEM
// pipe, one fetch per wave) — R12 of the prior session proved this path.
typedef const float __attribute__((address_space(4))) * fcp;

__device__ __forceinline__ fcp msel(const float* Tm, int step,
                                    unsigned long long sm) {
    int spin = (int)((sm >> step) & 1ull);
    return (fcp)(unsigned long long)(const void*)
        (Tm + (size_t)(step * 2 + spin) * 256);
}

// Pre-transpose T[site][spin][u=x][r=gp][d=z][l=g] into
// Tm[(site*2+spin)*256 + (gp*4+z)*16 + (g*4+x)]  (73,728 B in d_ws).
__global__ void peps_reorder_kernel(const float* __restrict__ T,
                                    float* __restrict__ Tm)
{
    int idx = blockIdx.x * 256 + threadIdx.x;   // [0, 18432)
    if (idx >= NSITE * 2 * 256) return;
    int i  = idx & 15;          // i = g*4 + x
    int o  = (idx >> 4) & 15;   // o = gp*4 + z
    int sp = (idx >> 8) & 1;
    int st = idx >> 9;
    int g = i >> 2, x = i & 3, gp = o >> 2, z = o & 3;
    Tm[idx] = T[st * 512 + sp * 256 + x * 64 + gp * 16 + z * 4 + g];
}

// ---- Fused middle-row pair (c=0, c=1): step0 has GIN=1 (state lives in the
// g0 plane), step1 GIN=4. Unit = one thread = fixed digits 2..5 (base=t<<4).
// Reads 16 floats (4 quads), writes 64 (16 quads); both matrices applied
// register-resident. Thread's read set == its write set => no intra-phase
// cross-thread races (LDS ops are in-order per wave, per-thread here).
__device__ __forceinline__ void mid_first(float* __restrict__ W, fcp M0,
                                          fcp M1, int base)
{
    float U[4][4];               // [x1][x0]
    #pragma unroll
    for (int x1 = 0; x1 < 4; ++x1) {
        float4 q = *(const float4*)&W[SWZ(base + 4 * x1)];   // g=0 plane
        U[x1][0] = q.x; U[x1][1] = q.y; U[x1][2] = q.z; U[x1][3] = q.w;
    }
    float V[4][4][4];            // [gp][z0][x1]
    #pragma unroll
    for (int gp = 0; gp < 4; ++gp)
        #pragma unroll
        for (int z0 = 0; z0 < 4; ++z0)
            #pragma unroll
            for (int x1 = 0; x1 < 4; ++x1) {
                float acc = 0.f;
                #pragma unroll
                for (int x0 = 0; x0 < 4; ++x0)
                    acc += M0[(gp * 4 + z0) * 16 + x0] * U[x1][x0];
                V[gp][z0][x1] = acc;
            }
    #pragma unroll
    for (int gp1 = 0; gp1 < 4; ++gp1)
        #pragma unroll
        for (int z1 = 0; z1 < 4; ++z1) {
            float o[4];
            #pragma unroll
            for (int z0 = 0; z0 < 4; ++z0) {
                float acc = 0.f;
                #pragma unroll
                for (int gp = 0; gp < 4; ++gp)
                    #pragma unroll
                    for (int x1 = 0; x1 < 4; ++x1)
                        acc += M1[(gp1 * 4 + z1) * 16 + gp * 4 + x1]
                             * V[gp][z0][x1];
                o[z0] = acc;
            }
            *(float4*)&W[gp1 * 4096 + SWZ(base + 4 * z1)] =
                make_float4(o[0], o[1], o[2], o[3]);
        }
}

// ---- Fused middle-row pair (c, c+1), c>=2: S = 4^c dword stride of the
// first digit. LAST=true for the (4,5) pair where step c+1 collapses g
// (GOUT=1, result written to the g0 plane only). Loop order keeps each
// 16-float M row loop-invariant (one s_load_dwordx16, reused 4x).
template<int S, bool LAST>
__device__ __forceinline__ void mid_pair(float* __restrict__ W, fcp Ma, fcp Mb,
                                         int base)
{
    float U[4][4][4];            // [g][xa][xb]
    #pragma unroll
    for (int g = 0; g < 4; ++g)
        #pragma unroll
        for (int xa = 0; xa < 4; ++xa)
            #pragma unroll
            for (int xb = 0; xb < 4; ++xb)
                U[g][xa][xb] = W[g * 4096 + SWZ(base + S * xa + 4 * S * xb)];
    float V[4][4][4];            // [gp][za][xb]
    #pragma unroll
    for (int gp = 0; gp < 4; ++gp)
        #pragma unroll
        for (int za = 0; za < 4; ++za)
            #pragma unroll
            for (int xb = 0; xb < 4; ++xb) {
                float acc = 0.f;
                #pragma unroll
                for (int g = 0; g < 4; ++g)
                    #pragma unroll
                    for (int xa = 0; xa < 4; ++xa)
                        acc += Ma[(gp * 4 + za) * 16 + g * 4 + xa]
                             * U[g][xa][xb];
                V[gp][za][xb] = acc;
            }
    #pragma unroll
    for (int gb = 0; gb < (LAST ? 1 : 4); ++gb)
        #pragma unroll
        for (int zb = 0; zb < 4; ++zb)
            #pragma unroll
            for (int za = 0; za < 4; ++za) {
                float acc = 0.f;
                #pragma unroll
                for (int gp = 0; gp < 4; ++gp)
                    #pragma unroll
                    for (int xb = 0; xb < 4; ++xb)
                        acc += Mb[(gb * 4 + zb) * 16 + gp * 4 + xb]
                             * V[gp][za][xb];
                W[gb * 4096 + SWZ(base + S * za + 4 * S * zb)] = acc;
            }
}

// Fixed-slot in-place contraction, R2 restructure: state index =
// g*4096 + SWZ(sum_j slot_j*4^j). Steps are fused in PAIRS — each phase
// applies two 16x16 site matrices with the intermediate register-resident:
// 17 barriers instead of 36 (R1 showed per-phase idle ~2800 cyc dominates;
// wave count was not the lever). One thread owns the full 64-float
// (g, x_c, x_{c+1}) closure of its unit => no intra-phase races, and all
// M indices are compile-time offsets off a wave-uniform base (s_load path).
// 256 threads; 2 blocks/CU (LDS-bound), 2 waves/SIMD.
__global__ __launch_bounds__(256, 2)
void peps_amp_kernel(const int* __restrict__ X, const float* __restrict__ Tm,
                     float* __restrict__ out)
{
    __shared__ float W[16384];   // 65536 B exactly (4^7 fixed-slot state)

    const int b = blockIdx.x;
    const int t = threadIdx.x;
    const int* xrow = X + b * NSITE;

    // PHYS=2: pack the 36 spins into one scalar 64-bit mask (SGPR-resident
    // so every Tm address below is provably wave-uniform).
    unsigned long long sm = 0ull;
    const int4* xp = (const int4*)xrow;
    #pragma unroll
    for (int k = 0; k < 9; ++k) {
        int4 v = xp[k];
        sm |= ((unsigned long long)(v.x & 1)) << (4 * k + 0);
        sm |= ((unsigned long long)(v.y & 1)) << (4 * k + 1);
        sm |= ((unsigned long long)(v.z & 1)) << (4 * k + 2);
        sm |= ((unsigned long long)(v.w & 1)) << (4 * k + 3);
    }
    {
        unsigned lo = __builtin_amdgcn_readfirstlane((int)(sm & 0xffffffffull));
        unsigned hi = __builtin_amdgcn_readfirstlane((int)(sm >> 32));
        sm = ((unsigned long long)hi << 32) | lo;
    }

    // ---- row 0: three fused phases (state grows from scalar) ----
    if (t == 0) {                // pair (0,0)-(0,1): single unit
        fcp M0 = msel(Tm, 0, sm), M1 = msel(Tm, 1, sm);
        float V[4][4];           // [gp][z0]  (seed state == 1.0)
        #pragma unroll
        for (int gp = 0; gp < 4; ++gp)
            #pragma unroll
            for (int z0 = 0; z0 < 4; ++z0)
                V[gp][z0] = M0[(gp * 4 + z0) * 16];
        #pragma unroll
        for (int gp1 = 0; gp1 < 4; ++gp1)
            #pragma unroll
            for (int z1 = 0; z1 < 4; ++z1) {
                float o[4];
                #pragma unroll
                for (int z0 = 0; z0 < 4; ++z0) {
                    float acc = 0.f;
                    #pragma unroll
                    for (int gp = 0; gp < 4; ++gp)
                        acc += M1[(gp1 * 4 + z1) * 16 + gp * 4] * V[gp][z0];
                    o[z0] = acc;
                }
                *(float4*)&W[gp1 * 4096 + SWZ(4 * z1)] =
                    make_float4(o[0], o[1], o[2], o[3]);
            }
    }
    __syncthreads();
    if (t < 16) {                // pair (0,2)-(0,3): 16 units (spect z0,z1)
        fcp M2 = msel(Tm, 2, sm), M3 = msel(Tm, 3, sm);
        float U[4];
        #pragma unroll
        for (int g = 0; g < 4; ++g) U[g] = W[g * 4096 + SWZ(t)];
        float V[4][4];           // [gp][z2]
        #pragma unroll
        for (int gp = 0; gp < 4; ++gp)
            #pragma unroll
            for (int z2 = 0; z2 < 4; ++z2) {
                float acc = 0.f;
                #pragma unroll
                for (int g = 0; g < 4; ++g)
                    acc += M2[(gp * 4 + z2) * 16 + g * 4] * U[g];
                V[gp][z2] = acc;
            }
        #pragma unroll
        for (int gp3 = 0; gp3 < 4; ++gp3)
            #pragma unroll
            for (int z3 = 0; z3 < 4; ++z3)
                #pragma unroll
                for (int z2 = 0; z2 < 4; ++z2) {
                    float acc = 0.f;
                    #pragma unroll
                    for (int gp = 0; gp < 4; ++gp)
                        acc += M3[(gp3 * 4 + z3) * 16 + gp * 4] * V[gp][z2];
                    W[gp3 * 4096 + SWZ(t + 16 * z2 + 64 * z3)] = acc;
                }
    }
    __syncthreads();
    {                            // pair (0,4)-(0,5): 256 units, g collapses
        fcp M4 = msel(Tm, 4, sm), M5 = msel(Tm, 5, sm);
        float U[4];
        #pragma unroll
        for (int g = 0; g < 4; ++g) U[g] = W[g * 4096 + SWZ(t)];
        float V[4][4];           // [gp][z4]
        #pragma unroll
        for (int gp = 0; gp < 4; ++gp)
            #pragma unroll
            for (int z4 = 0; z4 < 4; ++z4) {
                float acc = 0.f;
                #pragma unroll
                for (int g = 0; g < 4; ++g)
                    acc += M4[(gp * 4 + z4) * 16 + g * 4] * U[g];
                V[gp][z4] = acc;
            }
        #pragma unroll
        for (int z5 = 0; z5 < 4; ++z5)
            #pragma unroll
            for (int z4 = 0; z4 < 4; ++z4) {
                float acc = 0.f;
                #pragma unroll
                for (int gp = 0; gp < 4; ++gp)
                    acc += M5[z5 * 16 + gp * 4] * V[gp][z4];
                W[SWZ(t + 256 * z4 + 1024 * z5)] = acc;    // g0 plane
            }
    }

    // ---- rows 1..4: three fused phases each ----
    #pragma unroll 1
    for (int row = 1; row <= 4; ++row) {
        const int s0 = row * 6;
        __syncthreads();
        mid_first(W, msel(Tm, s0, sm), msel(Tm, s0 + 1, sm), t << 4);
        __syncthreads();
        mid_pair<16, false>(W, msel(Tm, s0 + 2, sm), msel(Tm, s0 + 3, sm),
                            (t & 15) | ((t >> 4) << 8));
        __syncthreads();
        mid_pair<256, true>(W, msel(Tm, s0 + 4, sm), msel(Tm, s0 + 5, sm), t);
    }

    // ---- row 5: three fused phases; result written straight to out[b] ----
    __syncthreads();
    {                            // pair (5,0)-(5,1): 256 units
        fcp M0 = msel(Tm, 30, sm), M1 = msel(Tm, 31, sm);
        const int base = t << 4;
        float V[4][4];           // [gp][x1]
        #pragma unroll
        for (int x1 = 0; x1 < 4; ++x1) {
            float4 q = *(const float4*)&W[SWZ(base + 4 * x1)];
            float U[4] = {q.x, q.y, q.z, q.w};
            #pragma unroll
            for (int gp = 0; gp < 4; ++gp) {
                float acc = 0.f;
                #pragma unroll
                for (int x0 = 0; x0 < 4; ++x0)
                    acc += M0[gp * 64 + x0] * U[x0];
                V[gp][x1] = acc;
            }
        }
        #pragma unroll
        for (int gp1 = 0; gp1 < 4; ++gp1) {
            float acc = 0.f;
            #pragma unroll
            for (int gp = 0; gp < 4; ++gp)
                #pragma unroll
                for (int x1 = 0; x1 < 4; ++x1)
                    acc += M1[gp1 * 64 + gp * 4 + x1] * V[gp][x1];
            W[gp1 * 4096 + SWZ(base)] = acc;
        }
    }
    __syncthreads();
    if (t < 16) {                // pair (5,2)-(5,3): 16 units (x4,x5)
        fcp M2 = msel(Tm, 32, sm), M3 = msel(Tm, 33, sm);
        float V[4][4];           // [gp][x3]
        #pragma unroll
        for (int x3 = 0; x3 < 4; ++x3) {
            #pragma unroll
            for (int gp = 0; gp < 4; ++gp) V[gp][x3] = 0.f;
            #pragma unroll
            for (int x2 = 0; x2 < 4; ++x2) {
                float U[4];
                #pragma unroll
                for (int g = 0; g < 4; ++g)
                    U[g] = W[g * 4096 + SWZ((x2 + 4 * x3 + 16 * t) << 4)];
                #pragma unroll
                for (int gp = 0; gp < 4; ++gp)
                    #pragma unroll
                    for (int g = 0; g < 4; ++g)
                        V[gp][x3] += M2[gp * 64 + g * 4 + x2] * U[g];
            }
        }
        #pragma unroll
        for (int gp3 = 0; gp3 < 4; ++gp3) {
            float acc = 0.f;
            #pragma unroll
            for (int gp = 0; gp < 4; ++gp)
                #pragma unroll
                for (int x3 = 0; x3 < 4; ++x3)
                    acc += M3[gp3 * 64 + gp * 4 + x3] * V[gp][x3];
            W[gp3 * 4096 + SWZ(t << 8)] = acc;
        }
    }
    __syncthreads();
    if (t == 0) {                // pair (5,4)-(5,5): final scalar
        fcp M4 = msel(Tm, 34, sm), M5 = msel(Tm, 35, sm);
        float V[4][4];           // [gp][x5]
        #pragma unroll
        for (int x5 = 0; x5 < 4; ++x5) {
            #pragma unroll
            for (int gp = 0; gp < 4; ++gp) V[gp][x5] = 0.f;
            #pragma unroll
            for (int x4 = 0; x4 < 4; ++x4) {
                float U[4];
                #pragma unroll
                for (int g = 0; g < 4; ++g)
                    U[g] = W[g * 4096 + SWZ((x4 + 4 * x5) << 8)];
                #pragma unroll
                for (int gp = 0; gp < 4; ++gp)
                    #pragma unroll
                    for (int g = 0; g < 4; ++g)
                        V[gp][x5] += M4[gp * 64 + g * 4 + x4] * U[g];
            }
        }
        float r = 0.f;
        #pragma unroll
        for (int gp = 0; gp < 4; ++gp)
            #pragma unroll
            for (int x5 = 0; x5 < 4; ++x5)
                r += M5[gp * 4 + x5] * V[gp][x5];
        out[b] = r;
    }
}

extern "C" void kernel_launch(void* const* d_in, const int* in_sizes, int n_in,
                              void* d_out, int out_size, void* d_ws, size_t ws_size,
                              hipStream_t stream) {
    const int*   X  = (const int*)d_in[0];     // x: [1024, 36] int32
    const float* Tg = (const float*)d_in[1];   // T: [6,6,2,4,4,4,4] fp32
    float* out = (float*)d_out;                // reference output: float32
    float* Tm  = (float*)d_ws;                 // 73,728 B scratch
    (void)in_sizes; (void)n_in; (void)ws_size; (void)out_size;
    peps_reorder_kernel<<<dim3(72), dim3(256), 0, stream>>>(Tg, Tm);
    peps_amp_kernel<<<dim3(BATCH), dim3(256), 0, stream>>>(X, Tm, out);
}